// Round 5
// baseline (189.456 us; speedup 1.0000x reference)
//
#include <hip/hip_runtime.h>

#define D      128
#define DM     64
#define DMLP   512
#define PMAX   150
#define VOC    152
#define EQT    151
#define NBATCH 65536

typedef __attribute__((ext_vector_type(8))) __bf16 bf16x8;
typedef __attribute__((ext_vector_type(4))) float  f32x4;

__device__ __forceinline__ float silu_f(float x){ return x / (1.0f + expf(-x)); }

// ---- workspace layout (float-slot offsets) ----
#define OFF_MEMVEC 0        // 150*128 f32
#define OFF_X3BASE 19200    // 128 f32
#define OFF_KE     19328    // 152*128 f32
#define OFF_KP     38784    // 4*128 f32
#define OFF_SC     39296    // 150*624 f32
#define OFF_O0     132896   // 150*512 bf16
#define OFF_O1     171296   // 150*512 bf16
#define OFF_O2     209696   // 150*512 bf16
#define OFF_O3     248096   // 512 bf16
#define OFF_M3B    248352   // 150*128 bf16
#define OFF_W1F    257952   // 65536 bf16 frag-packed (chunk-contiguous)
#define OFF_W2F    290720   // 65536 bf16 frag-packed K-major (chunk-contiguous)
#define OFF_WUF    323488   // 20480 bf16

// ===== P1a: memvec + x3base + K tables (307 blocks x 256) ====================
__global__ void k_P1a(const float* __restrict__ tok, const float* __restrict__ pos,
                      const float* __restrict__ W_mem, const float* __restrict__ b_mem,
                      const float* __restrict__ W_sur, const float* __restrict__ b_sur,
                      const float* __restrict__ W_m2r, const float* __restrict__ b_m2r,
                      const float* __restrict__ W_K,
                      float* __restrict__ memvec, float* __restrict__ x3base,
                      float* __restrict__ KE, float* __restrict__ KP)
{
    int r = blockIdx.x, t = threadIdx.x;
    if (r < 150) {
        int p = r;
        __shared__ float sx0[D], sz[DM], sdiff[D], szu[DM];
        if (t < D) sx0[t] = tok[p*D + t] + pos[t];
        __syncthreads();
        if (t < DM) {
            float acc = b_mem[t];
            for (int d = 0; d < D; d++) acc += sx0[d] * W_mem[d*DM + t];
            sz[t] = silu_f(acc);
        }
        __syncthreads();
        if (t < D) {
            float acc = b_sur[t];
            for (int j = 0; j < DM; j++) acc += sz[j] * W_sur[j*D + t];
            sdiff[t] = sx0[t] - acc;
        }
        __syncthreads();
        if (t < DM) {
            float acc = 0.f;
            for (int d = 0; d < D; d++) acc += sdiff[d] * W_mem[d*DM + t];
            szu[t] = sz[t] + silu_f(acc);
        }
        __syncthreads();
        if (t < D) {
            float acc = b_m2r[t];
            for (int j = 0; j < DM; j++) acc += szu[j] * W_m2r[j*D + t];
            memvec[p*D + t] = acc;
        }
    } else if (r == 150) {
        if (t < D) x3base[t] = tok[EQT*D + t] + pos[3*D + t];
    } else {
        int idx = r - 151;
        const float* src = (idx < 152) ? (tok + idx*D) : (pos + (idx-152)*D);
        float*       dst = (idx < 152) ? (KE + idx*D)  : (KP + (idx-152)*D);
        __shared__ float s[D];
        if (t < D) s[t] = src[t];
        __syncthreads();
        if (t < D) {
            int h = t >> 5, k = t & 31;
            float acc = 0.f;
            for (int d = 0; d < D; d++) acc += s[d] * W_K[h*4096 + d*32 + k];
            dst[t] = acc;
        }
    }
}

// ===== P2x: SC/M3B (blocks 0-299) + O-tables + weight repack (blocks 300-824)
__global__ void k_P2x(const float* __restrict__ memvec, const float* __restrict__ x3base,
                      const float* __restrict__ W_Q, const float* __restrict__ W_V,
                      const float* __restrict__ W_O,
                      const float* __restrict__ KE, const float* __restrict__ KP,
                      const float* __restrict__ tok, const float* __restrict__ pos,
                      const float* __restrict__ W1, const float* __restrict__ W2,
                      const float* __restrict__ WU,
                      float* __restrict__ SC, __bf16* __restrict__ M3B,
                      __bf16* __restrict__ O0, __bf16* __restrict__ O1,
                      __bf16* __restrict__ O2, __bf16* __restrict__ O3,
                      __bf16* __restrict__ W1f, __bf16* __restrict__ W2f, __bf16* __restrict__ WUf)
{
    int r = blockIdx.x, t = threadIdx.x;
    if (r < 300) {
        int p = r >> 1, half = r & 1;
        __shared__ float sMem[D], sIn[D], sQ3[D], sMV[D];
        if (t < D) { float m = memvec[p*D + t]; sMem[t] = m; sIn[t] = m + x3base[t]; }
        __syncthreads();
        if (t < D) {
            int h = t >> 5, k = t & 31;
            float acc = 0.f;
            for (int d = 0; d < D; d++) acc += sIn[d] * W_Q[h*4096 + d*32 + k];
            sQ3[t] = acc;
        } else {
            int c = t - D; int h = c >> 5, k = c & 31;
            float acc = 0.f;
            for (int d = 0; d < D; d++) acc += sMem[d] * W_V[h*4096 + d*32 + k];
            sMV[c] = acc;
        }
        __syncthreads();
        const float scale = 0.17677669529663687f;
        for (int ii = t; ii < 312; ii += 256) {
            int i = half*312 + ii;
            int v = i >> 2, h = i & 3;
            const float4* qh = (const float4*)(sQ3 + h*32);
            float4 s4 = {0.f, 0.f, 0.f, 0.f};
            if (v < 152) {
                const float4* ke = (const float4*)(KE + v*D + h*32);
                #pragma unroll
                for (int k = 0; k < 8; k++) {
                    float4 q = qh[k], e = ke[k];
                    s4.x += q.x*e.x; s4.y += q.y*e.y; s4.z += q.z*e.z; s4.w += q.w*e.w;
                }
            } else if (v == 152 || v == 153) {
                const float4* ke = (const float4*)(KE + ((v==152)? p : EQT)*D + h*32);
                const float4* kp = (const float4*)(KP + ((v==152)? 0 : 3)*D + h*32);
                #pragma unroll
                for (int k = 0; k < 8; k++) {
                    float4 q = qh[k], e = ke[k], pp = kp[k];
                    s4.x += q.x*(e.x+pp.x); s4.y += q.y*(e.y+pp.y);
                    s4.z += q.z*(e.z+pp.z); s4.w += q.w*(e.w+pp.w);
                }
            } else {
                const float4* kp = (const float4*)(KP + ((v==154)?1:2)*D + h*32);
                #pragma unroll
                for (int k = 0; k < 8; k++) {
                    float4 q = qh[k], pp = kp[k];
                    s4.x += q.x*pp.x; s4.y += q.y*pp.y; s4.z += q.z*pp.z; s4.w += q.w*pp.w;
                }
            }
            SC[p*624 + i] = (s4.x + s4.y + s4.z + s4.w) * scale;
        }
        if (half == 0 && t < D) {
            float acc = sIn[t];
            for (int c = 0; c < D; c++) acc += sMV[c] * W_O[c*D + t];
            M3B[p*D + t] = (__bf16)acc;
        }
        return;
    }
    int rr = r - 300;
    if (rr < 451) {
        int idx = rr;
        int tt, v; __bf16* outp;
        if (idx < 150)      { tt = 0; v = idx;       outp = O0 + v*512; }
        else if (idx < 300) { tt = 1; v = idx - 150; outp = O1 + (idx-150)*512; }
        else if (idx < 450) { tt = 2; v = idx - 300; outp = O2 + (idx-300)*512; }
        else                { tt = 3; v = EQT;       outp = O3; }
        __shared__ float sTP[D], sv[D];
        if (t < D) sTP[t] = tok[v*D + t] + pos[tt*D + t];
        __syncthreads();
        if (t < D) {
            int h = t >> 5, k = t & 31;
            float acc = 0.f;
            for (int d = 0; d < D; d++) acc += sTP[d] * W_V[h*4096 + d*32 + k];
            sv[t] = acc;
        }
        __syncthreads();
        #pragma unroll
        for (int i = 0; i < 2; i++) {
            int c = t + i*256;
            int h = c >> 7, m = c & 127;
            float acc = 0.f;
            for (int k = 0; k < 32; k++) acc += sv[h*32 + k] * W_O[h*4096 + k*128 + m];
            outp[c] = (__bf16)acc;
        }
    } else if (rr < 483) {
        int f = (rr-451)*256 + t;                      // W1 128x512, f=(nbg*4+kb)*64+l
        int l = f & 63, kb = (f>>6) & 3, nb = f >> 8;
        int k0 = kb*32 + (l>>4)*8, n = nb*16 + (l&15);
        #pragma unroll
        for (int j = 0; j < 8; j++) W1f[f*8 + j] = (__bf16)W1[(k0+j)*DMLP + n];
    } else if (rr < 515) {
        int f = (rr-483)*256 + t;                      // W2 512x128, K-MAJOR: f=(kb*8+nb)*64+l
        int l = f & 63, g = f >> 6;
        int nb = g & 7, kb = g >> 3;
        int k0 = kb*32 + (l>>4)*8, n = nb*16 + (l&15);
        #pragma unroll
        for (int j = 0; j < 8; j++) W2f[f*8 + j] = (__bf16)W2[(k0+j)*D + n];
    } else {
        int f = (rr-515)*256 + t;                      // W_un 128x150 (N pad 160), f=(nt*4+kb)*64+l
        int l = f & 63, kb = (f>>6) & 3, nb = f >> 8;
        int k0 = kb*32 + (l>>4)*8, n = nb*16 + (l&15);
        #pragma unroll
        for (int j = 0; j < 8; j++) WUf[f*8 + j] = (__bf16)((n < 150) ? WU[(k0+j)*150 + n] : 0.f);
    }
}

// ===== FUSED v3: BARRIER-FREE attention + MLP + unembed =====================
// 1024 blocks x 256 thr, 64 samples/block, 4 blocks/CU (16 waves/CU).
// ZERO __syncthreads: W1f/W2f/WUf fragments are read straight from global
// (coalesced b128, L2/L1-hot — 276 KB total working set), biases from global,
// and ALL LDS regions are WAVE-PRIVATE 4 KB slices:
//   sW = smem + wv*4096:
//     phase A : x3 panel, 16 rows x 256 B (XOR-swizzled) — wave's own rows
//     chunks  : H panel, 16 x 40 bf16 (1.28 KB) in the dead x3 space
//     epilogue: x'' panel, 16 rows x 256 B (XOR-swizzled)
// Same-wave LDS RAW ordered by s_waitcnt lgkmcnt(0) + sched_barrier(0)
// (rule #18). Rationale: R4's counters showed no pipe >30% — the 16-chunk x
// 2-barrier lockstep schedule was the serializer, not any bandwidth.
__global__ __launch_bounds__(256, 4) void k_fused(
    const int* __restrict__ p_val, const int* __restrict__ a_tok, const int* __restrict__ b_tok,
    const float* __restrict__ SC, const __bf16* __restrict__ O0, const __bf16* __restrict__ O1,
    const __bf16* __restrict__ O2, const __bf16* __restrict__ O3g, const __bf16* __restrict__ M3B,
    const __bf16* __restrict__ W1f, const __bf16* __restrict__ W2f, const __bf16* __restrict__ WUf,
    const float* __restrict__ b1, const float* __restrict__ b2, const float* __restrict__ bun,
    float* __restrict__ out)
{
    __shared__ __align__(16) char smem[16384];

    int tid = threadIdx.x;
    int wv = tid >> 6, l = tid & 63, lr = l & 15, quad = l >> 4;
    int tbase = blockIdx.x * 64 + wv * 16;
    char* sW = smem + wv*4096;             // wave-private slice

    // ---------- phase A: attention for this wave's 16 samples ----------
    {
        int sl = l >> 2, h = l & 3;        // 16 samples/wave, 4 lanes each
        int gs = tbase + sl;
        int p = p_val[gs], ta = a_tok[gs], tb = b_tok[gs];

        float wloc[4];
        {
            const float* SCp = SC + p*624;
            float sc0 = SCp[608 + h];
            float sc3 = SCp[612 + h];
            float sc1 = SCp[ta*4 + h] + SCp[616 + h];
            float sc2 = SCp[tb*4 + h] + SCp[620 + h];
            float mx = fmaxf(fmaxf(sc0, sc1), fmaxf(sc2, sc3));
            float e0 = expf(sc0-mx), e1 = expf(sc1-mx), e2 = expf(sc2-mx), e3 = expf(sc3-mx);
            float inv = 1.f / (e0 + e1 + e2 + e3);
            wloc[0] = e0*inv; wloc[1] = e1*inv; wloc[2] = e2*inv; wloc[3] = e3*inv;
        }
        float w[16];
        #pragma unroll
        for (int j = 0; j < 4; j++) w[h*4 + j] = wloc[j];
        #pragma unroll
        for (int m = 1; m < 4; m++) {
            int oh = h ^ m;
            #pragma unroll
            for (int j = 0; j < 4; j++) w[oh*4 + j] = __shfl_xor(wloc[j], m);
        }

        const bf16x8* m3v = (const bf16x8*)(M3B + p*128);
        const bf16x8* t0  = (const bf16x8*)(O0 + p*512);
        const bf16x8* t1  = (const bf16x8*)(O1 + ta*512);
        const bf16x8* t2  = (const bf16x8*)(O2 + tb*512);
        const bf16x8* t3  = (const bf16x8*)O3g;
        #pragma unroll
        for (int jj = 0; jj < 4; jj++) {
            int c8 = h*4 + jj;
            bf16x8 mv = m3v[c8];
            float v[8];
            #pragma unroll
            for (int e = 0; e < 8; e++) v[e] = (float)mv[e];
            #pragma unroll
            for (int hh = 0; hh < 4; hh++) {
                int o8 = hh*16 + c8;
                bf16x8 e0 = t0[o8], e1 = t1[o8], e2 = t2[o8], e3 = t3[o8];
                float w0 = w[hh*4+0], w1 = w[hh*4+1], w2 = w[hh*4+2], w3 = w[hh*4+3];
                #pragma unroll
                for (int e = 0; e < 8; e++)
                    v[e] += w0*(float)e0[e] + w1*(float)e1[e] + w2*(float)e2[e] + w3*(float)e3[e];
            }
            bf16x8 st;
            #pragma unroll
            for (int e = 0; e < 8; e++) st[e] = (__bf16)v[e];
            *(bf16x8*)(sW + sl*256 + ((c8*16) ^ ((sl&7)<<4))) = st;
        }
    }
    asm volatile("s_waitcnt lgkmcnt(0)" ::: "memory");
    __builtin_amdgcn_sched_barrier(0);

    // ---------- A-fragments from wave-private panel ----------
    bf16x8 a[4];
    #pragma unroll
    for (int kb = 0; kb < 4; kb++)
        a[kb] = *(const bf16x8*)(sW + lr*256 + ((kb*64 + quad*16) ^ ((lr&7)<<4)));
    asm volatile("s_waitcnt lgkmcnt(0)" ::: "memory");
    __builtin_amdgcn_sched_barrier(0);                 // a[] captured; x3 space reusable

    f32x4 acc2[8];
    #pragma unroll
    for (int i = 0; i < 8; i++) acc2[i] = (f32x4){0.f, 0.f, 0.f, 0.f};

    // ---------- barrier-free MLP chunk loop, W straight from global ----------
    for (int cc = 0; cc < 16; cc++) {
        // MLP1: 2 col-groups of 16; w1 fragments from global (L1/L2-hot)
        #pragma unroll
        for (int nbl = 0; nbl < 2; nbl++) {
            float bv = b1[cc*32 + nbl*16 + lr];
            f32x4 acc = (f32x4){bv, bv, bv, bv};
            #pragma unroll
            for (int kb = 0; kb < 4; kb++) {
                bf16x8 w1 = *(const bf16x8*)(W1f + cc*4096 + ((nbl*4 + kb)*64 + l)*8);
                acc = __builtin_amdgcn_mfma_f32_16x16x32_bf16(a[kb], w1, acc, 0, 0, 0);
            }
            #pragma unroll
            for (int r = 0; r < 4; r++)
                *(__bf16*)(sW + (((quad*4 + r)*40) + nbl*16 + lr)*2) = (__bf16)fmaxf(acc[r], 0.f);
        }
        asm volatile("s_waitcnt lgkmcnt(0)" ::: "memory");
        __builtin_amdgcn_sched_barrier(0);
        // MLP2 partial: this chunk's 32-wide K block; w2 fragments from global
        {
            bf16x8 h = *(const bf16x8*)(sW + (lr*40 + quad*8)*2);
            #pragma unroll
            for (int nb2 = 0; nb2 < 8; nb2++) {
                bf16x8 w2 = *(const bf16x8*)(W2f + cc*4096 + (nb2*64 + l)*8);
                acc2[nb2] = __builtin_amdgcn_mfma_f32_16x16x32_bf16(h, w2, acc2[nb2], 0, 0, 0);
            }
        }
    }

    // residual via identity-matrix MFMA
    #pragma unroll
    for (int nb2 = 0; nb2 < 8; nb2++) {
        int kb = nb2 >> 1;
        bf16x8 bi;
        #pragma unroll
        for (int j = 0; j < 8; j++)
            bi[j] = (kb*32 + quad*8 + j == nb2*16 + lr) ? (__bf16)1.0f : (__bf16)0.0f;
        acc2[nb2] = __builtin_amdgcn_mfma_f32_16x16x32_bf16(a[kb], bi, acc2[nb2], 0, 0, 0);
    }

    // x'' = acc2 + b2 -> wave-private swizzled panel (16 rows x 256 B)
    #pragma unroll
    for (int nb2 = 0; nb2 < 8; nb2++) {
        int n = nb2*16 + lr;
        float bv = b2[n];
        #pragma unroll
        for (int r = 0; r < 4; r++) {
            float v = acc2[nb2][r] + bv;
            int row = quad*4 + r;
            *(__bf16*)(sW + row*256 + ((n*2) ^ ((row&7)<<4))) = (__bf16)v;
        }
    }
    asm volatile("s_waitcnt lgkmcnt(0)" ::: "memory");
    __builtin_amdgcn_sched_barrier(0);
    bf16x8 au[4];
    #pragma unroll
    for (int kb = 0; kb < 4; kb++)
        au[kb] = *(const bf16x8*)(sW + lr*256 + ((kb*64 + quad*16) ^ ((lr&7)<<4)));

    // unembed: WU fragments straight from global
    for (int nt = 0; nt < 10; nt++) {
        int n = nt*16 + lr;
        float bv = (n < 150) ? bun[n] : 0.f;
        f32x4 acc = (f32x4){bv, bv, bv, bv};
        #pragma unroll
        for (int kb = 0; kb < 4; kb++) {
            bf16x8 wu = *(const bf16x8*)(WUf + ((nt*4 + kb)*64 + l)*8);
            acc = __builtin_amdgcn_mfma_f32_16x16x32_bf16(au[kb], wu, acc, 0, 0, 0);
        }
        if (n < 150) {
            #pragma unroll
            for (int r = 0; r < 4; r++) {
                int rowg = tbase + quad*4 + r;
                out[rowg*150 + n] = acc[r];
            }
        }
    }
}

// ============================ launcher ======================================
extern "C" void kernel_launch(void* const* d_in, const int* in_sizes, int n_in,
                              void* d_out, int out_size, void* d_ws, size_t ws_size,
                              hipStream_t stream) {
    const int*   p_val = (const int*)d_in[0];
    const int*   a_tok = (const int*)d_in[1];
    const int*   b_tok = (const int*)d_in[2];
    const float* tok   = (const float*)d_in[3];
    const float* pos   = (const float*)d_in[4];
    const float* W_mem = (const float*)d_in[5];
    const float* b_mem = (const float*)d_in[6];
    const float* W_sur = (const float*)d_in[7];
    const float* b_sur = (const float*)d_in[8];
    const float* W_m2r = (const float*)d_in[9];
    const float* b_m2r = (const float*)d_in[10];
    const float* W_Q   = (const float*)d_in[11];
    const float* W_K   = (const float*)d_in[12];
    const float* W_V   = (const float*)d_in[13];
    const float* W_O   = (const float*)d_in[14];
    const float* W1    = (const float*)d_in[15];
    const float* b1    = (const float*)d_in[16];
    const float* W2    = (const float*)d_in[17];
    const float* b2    = (const float*)d_in[18];
    const float* WU    = (const float*)d_in[19];
    const float* bun   = (const float*)d_in[20];
    float* out = (float*)d_out;

    float* ws = (float*)d_ws;
    float* memvec = ws + OFF_MEMVEC;
    float* x3base = ws + OFF_X3BASE;
    float* KE     = ws + OFF_KE;
    float* KP     = ws + OFF_KP;
    float* SC     = ws + OFF_SC;
    __bf16* O0    = (__bf16*)(ws + OFF_O0);
    __bf16* O1    = (__bf16*)(ws + OFF_O1);
    __bf16* O2    = (__bf16*)(ws + OFF_O2);
    __bf16* O3    = (__bf16*)(ws + OFF_O3);
    __bf16* M3B   = (__bf16*)(ws + OFF_M3B);
    __bf16* W1f   = (__bf16*)(ws + OFF_W1F);
    __bf16* W2f   = (__bf16*)(ws + OFF_W2F);
    __bf16* WUf   = (__bf16*)(ws + OFF_WUF);

    k_P1a<<<307, 256, 0, stream>>>(tok, pos, W_mem, b_mem, W_sur, b_sur, W_m2r, b_m2r,
                                   W_K, memvec, x3base, KE, KP);
    k_P2x<<<825, 256, 0, stream>>>(memvec, x3base, W_Q, W_V, W_O, KE, KP,
                                   tok, pos, W1, W2, WU,
                                   SC, M3B, O0, O1, O2, O3, W1f, W2f, WUf);
    k_fused<<<NBATCH/64, 256, 0, stream>>>(p_val, a_tok, b_tok, SC, O0, O1, O2, O3, M3B,
                                           W1f, W2f, WUf, b1, b2, bun, out);
}

// Round 6
// 180.405 us; speedup vs baseline: 1.0502x; 1.0502x over previous
//
#include <hip/hip_runtime.h>

#define D      128
#define DM     64
#define DMLP   512
#define PMAX   150
#define VOC    152
#define EQT    151
#define NBATCH 65536

typedef __attribute__((ext_vector_type(8))) __bf16 bf16x8;
typedef __attribute__((ext_vector_type(4))) float  f32x4;

__device__ __forceinline__ float silu_f(float x){ return x / (1.0f + expf(-x)); }

// ---- workspace layout (float-slot offsets) ----
#define OFF_MEMVEC 0        // 150*128 f32
#define OFF_X3BASE 19200    // 128 f32
#define OFF_KE     19328    // 152*128 f32
#define OFF_KP     38784    // 4*128 f32
#define OFF_SC     39296    // 150*624 f32
#define OFF_O0     132896   // 150*512 bf16
#define OFF_O1     171296   // 150*512 bf16
#define OFF_O2     209696   // 150*512 bf16
#define OFF_O3     248096   // 512 bf16
#define OFF_M3B    248352   // 150*128 bf16
#define OFF_W1F    257952   // 65536 bf16 frag-packed (chunk-contiguous)
#define OFF_W2F    290720   // 65536 bf16 frag-packed K-major (chunk-contiguous)
#define OFF_WUF    323488   // 20480 bf16

// ===== P1a: memvec + x3base + K tables (307 blocks x 256) ====================
__global__ void k_P1a(const float* __restrict__ tok, const float* __restrict__ pos,
                      const float* __restrict__ W_mem, const float* __restrict__ b_mem,
                      const float* __restrict__ W_sur, const float* __restrict__ b_sur,
                      const float* __restrict__ W_m2r, const float* __restrict__ b_m2r,
                      const float* __restrict__ W_K,
                      float* __restrict__ memvec, float* __restrict__ x3base,
                      float* __restrict__ KE, float* __restrict__ KP)
{
    int r = blockIdx.x, t = threadIdx.x;
    if (r < 150) {
        int p = r;
        __shared__ float sx0[D], sz[DM], sdiff[D], szu[DM];
        if (t < D) sx0[t] = tok[p*D + t] + pos[t];
        __syncthreads();
        if (t < DM) {
            float acc = b_mem[t];
            for (int d = 0; d < D; d++) acc += sx0[d] * W_mem[d*DM + t];
            sz[t] = silu_f(acc);
        }
        __syncthreads();
        if (t < D) {
            float acc = b_sur[t];
            for (int j = 0; j < DM; j++) acc += sz[j] * W_sur[j*D + t];
            sdiff[t] = sx0[t] - acc;
        }
        __syncthreads();
        if (t < DM) {
            float acc = 0.f;
            for (int d = 0; d < D; d++) acc += sdiff[d] * W_mem[d*DM + t];
            szu[t] = sz[t] + silu_f(acc);
        }
        __syncthreads();
        if (t < D) {
            float acc = b_m2r[t];
            for (int j = 0; j < DM; j++) acc += szu[j] * W_m2r[j*D + t];
            memvec[p*D + t] = acc;
        }
    } else if (r == 150) {
        if (t < D) x3base[t] = tok[EQT*D + t] + pos[3*D + t];
    } else {
        int idx = r - 151;
        const float* src = (idx < 152) ? (tok + idx*D) : (pos + (idx-152)*D);
        float*       dst = (idx < 152) ? (KE + idx*D)  : (KP + (idx-152)*D);
        __shared__ float s[D];
        if (t < D) s[t] = src[t];
        __syncthreads();
        if (t < D) {
            int h = t >> 5, k = t & 31;
            float acc = 0.f;
            for (int d = 0; d < D; d++) acc += s[d] * W_K[h*4096 + d*32 + k];
            dst[t] = acc;
        }
    }
}

// ===== P2x: SC/M3B (blocks 0-299) + O-tables + weight repack (blocks 300-824)
__global__ void k_P2x(const float* __restrict__ memvec, const float* __restrict__ x3base,
                      const float* __restrict__ W_Q, const float* __restrict__ W_V,
                      const float* __restrict__ W_O,
                      const float* __restrict__ KE, const float* __restrict__ KP,
                      const float* __restrict__ tok, const float* __restrict__ pos,
                      const float* __restrict__ W1, const float* __restrict__ W2,
                      const float* __restrict__ WU,
                      float* __restrict__ SC, __bf16* __restrict__ M3B,
                      __bf16* __restrict__ O0, __bf16* __restrict__ O1,
                      __bf16* __restrict__ O2, __bf16* __restrict__ O3,
                      __bf16* __restrict__ W1f, __bf16* __restrict__ W2f, __bf16* __restrict__ WUf)
{
    int r = blockIdx.x, t = threadIdx.x;
    if (r < 300) {
        int p = r >> 1, half = r & 1;
        __shared__ float sMem[D], sIn[D], sQ3[D], sMV[D];
        if (t < D) { float m = memvec[p*D + t]; sMem[t] = m; sIn[t] = m + x3base[t]; }
        __syncthreads();
        if (t < D) {
            int h = t >> 5, k = t & 31;
            float acc = 0.f;
            for (int d = 0; d < D; d++) acc += sIn[d] * W_Q[h*4096 + d*32 + k];
            sQ3[t] = acc;
        } else {
            int c = t - D; int h = c >> 5, k = c & 31;
            float acc = 0.f;
            for (int d = 0; d < D; d++) acc += sMem[d] * W_V[h*4096 + d*32 + k];
            sMV[c] = acc;
        }
        __syncthreads();
        const float scale = 0.17677669529663687f;
        for (int ii = t; ii < 312; ii += 256) {
            int i = half*312 + ii;
            int v = i >> 2, h = i & 3;
            const float4* qh = (const float4*)(sQ3 + h*32);
            float4 s4 = {0.f, 0.f, 0.f, 0.f};
            if (v < 152) {
                const float4* ke = (const float4*)(KE + v*D + h*32);
                #pragma unroll
                for (int k = 0; k < 8; k++) {
                    float4 q = qh[k], e = ke[k];
                    s4.x += q.x*e.x; s4.y += q.y*e.y; s4.z += q.z*e.z; s4.w += q.w*e.w;
                }
            } else if (v == 152 || v == 153) {
                const float4* ke = (const float4*)(KE + ((v==152)? p : EQT)*D + h*32);
                const float4* kp = (const float4*)(KP + ((v==152)? 0 : 3)*D + h*32);
                #pragma unroll
                for (int k = 0; k < 8; k++) {
                    float4 q = qh[k], e = ke[k], pp = kp[k];
                    s4.x += q.x*(e.x+pp.x); s4.y += q.y*(e.y+pp.y);
                    s4.z += q.z*(e.z+pp.z); s4.w += q.w*(e.w+pp.w);
                }
            } else {
                const float4* kp = (const float4*)(KP + ((v==154)?1:2)*D + h*32);
                #pragma unroll
                for (int k = 0; k < 8; k++) {
                    float4 q = qh[k], pp = kp[k];
                    s4.x += q.x*pp.x; s4.y += q.y*pp.y; s4.z += q.z*pp.z; s4.w += q.w*pp.w;
                }
            }
            SC[p*624 + i] = (s4.x + s4.y + s4.z + s4.w) * scale;
        }
        if (half == 0 && t < D) {
            float acc = sIn[t];
            for (int c = 0; c < D; c++) acc += sMV[c] * W_O[c*D + t];
            M3B[p*D + t] = (__bf16)acc;
        }
        return;
    }
    int rr = r - 300;
    if (rr < 451) {
        int idx = rr;
        int tt, v; __bf16* outp;
        if (idx < 150)      { tt = 0; v = idx;       outp = O0 + v*512; }
        else if (idx < 300) { tt = 1; v = idx - 150; outp = O1 + (idx-150)*512; }
        else if (idx < 450) { tt = 2; v = idx - 300; outp = O2 + (idx-300)*512; }
        else                { tt = 3; v = EQT;       outp = O3; }
        __shared__ float sTP[D], sv[D];
        if (t < D) sTP[t] = tok[v*D + t] + pos[tt*D + t];
        __syncthreads();
        if (t < D) {
            int h = t >> 5, k = t & 31;
            float acc = 0.f;
            for (int d = 0; d < D; d++) acc += sTP[d] * W_V[h*4096 + d*32 + k];
            sv[t] = acc;
        }
        __syncthreads();
        #pragma unroll
        for (int i = 0; i < 2; i++) {
            int c = t + i*256;
            int h = c >> 7, m = c & 127;
            float acc = 0.f;
            for (int k = 0; k < 32; k++) acc += sv[h*32 + k] * W_O[h*4096 + k*128 + m];
            outp[c] = (__bf16)acc;
        }
    } else if (rr < 483) {
        int f = (rr-451)*256 + t;                      // W1 128x512, f=(nbg*4+kb)*64+l
        int l = f & 63, kb = (f>>6) & 3, nb = f >> 8;
        int k0 = kb*32 + (l>>4)*8, n = nb*16 + (l&15);
        #pragma unroll
        for (int j = 0; j < 8; j++) W1f[f*8 + j] = (__bf16)W1[(k0+j)*DMLP + n];
    } else if (rr < 515) {
        int f = (rr-483)*256 + t;                      // W2 512x128, K-MAJOR: f=(kb*8+nb)*64+l
        int l = f & 63, g = f >> 6;
        int nb = g & 7, kb = g >> 3;
        int k0 = kb*32 + (l>>4)*8, n = nb*16 + (l&15);
        #pragma unroll
        for (int j = 0; j < 8; j++) W2f[f*8 + j] = (__bf16)W2[(k0+j)*D + n];
    } else {
        int f = (rr-515)*256 + t;                      // W_un 128x150 (N pad 160), f=(nt*4+kb)*64+l
        int l = f & 63, kb = (f>>6) & 3, nb = f >> 8;
        int k0 = kb*32 + (l>>4)*8, n = nb*16 + (l&15);
        #pragma unroll
        for (int j = 0; j < 8; j++) WUf[f*8 + j] = (__bf16)((n < 150) ? WU[(k0+j)*150 + n] : 0.f);
    }
}

// ===== FUSED v4: 32 rows/wave + dbuf W + 1 barrier/chunk + async staging ====
// 512 blocks x 256 thr (4 waves), 128 samples/block, 32 rows/wave, 2 blocks/CU.
// LDS (49152 B):
//   [0,8192)       W1 buf0   | [8192,16384)  W1 buf1
//   [16384,24576)  W2 buf0   | [24576,32768) W2 buf1
//   [32768,43008)  H panels, 2560 B/wave (32 x 40 bf16)
//   [8192,40960)   phase-A x3 panel (128 x 256 B swizzled) — dead at barrier#1
//   [0,32768)      epilogue x'' panels (128 x 256 B swizzled) — after chunk loop
//   [32768,49152)  WU staging passes — after chunk loop
// Biases read from global (L1-hot). Per chunk: issue next-chunk loads -> 32
// MFMA compute -> ds_write other buf -> ONE barrier (T14: global latency hides
// under compute). Rationale: R4's LDS-read traffic (16 waves x full W re-read)
// was ~53% of cycles; 32 rows/wave halves it; dbuf halves barrier count.
__global__ __launch_bounds__(256, 2) void k_fused(
    const int* __restrict__ p_val, const int* __restrict__ a_tok, const int* __restrict__ b_tok,
    const float* __restrict__ SC, const __bf16* __restrict__ O0, const __bf16* __restrict__ O1,
    const __bf16* __restrict__ O2, const __bf16* __restrict__ O3g, const __bf16* __restrict__ M3B,
    const __bf16* __restrict__ W1f, const __bf16* __restrict__ W2f, const __bf16* __restrict__ WUf,
    const float* __restrict__ b1, const float* __restrict__ b2, const float* __restrict__ bun,
    float* __restrict__ out)
{
    __shared__ __align__(16) char smem[49152];
    char* sX3 = smem + 8192;               // x3 panel base (rows at row*256)

    int tid = threadIdx.x;
    int wv = tid >> 6, l = tid & 63, lr = l & 15, quad = l >> 4;
    int tbase = blockIdx.x * 128 + wv * 32;

    const char* gW1 = (const char*)W1f;
    const char* gW2 = (const char*)W2f;

    // chunk-0 staging loads issued FIRST — in flight during the attention phase
    float4 v0, v1, v2, v3;
    {
        const float4* g1 = (const float4*)gW1;
        const float4* g2 = (const float4*)gW2;
        v0 = g1[tid]; v1 = g1[tid + 256]; v2 = g2[tid]; v3 = g2[tid + 256];
    }

    // ---------- phase A: attention, 2 passes of 16 rows per wave ----------
    #pragma unroll
    for (int ss = 0; ss < 2; ss++) {
        int sl = l >> 2, h = l & 3;
        int row = wv*32 + ss*16 + sl;          // block-row; wave-private range
        int gs = blockIdx.x * 128 + row;
        int p = p_val[gs], ta = a_tok[gs], tb = b_tok[gs];

        float wloc[4];
        {
            const float* SCp = SC + p*624;
            float sc0 = SCp[608 + h];
            float sc3 = SCp[612 + h];
            float sc1 = SCp[ta*4 + h] + SCp[616 + h];
            float sc2 = SCp[tb*4 + h] + SCp[620 + h];
            float mx = fmaxf(fmaxf(sc0, sc1), fmaxf(sc2, sc3));
            float e0 = expf(sc0-mx), e1 = expf(sc1-mx), e2 = expf(sc2-mx), e3 = expf(sc3-mx);
            float inv = 1.f / (e0 + e1 + e2 + e3);
            wloc[0] = e0*inv; wloc[1] = e1*inv; wloc[2] = e2*inv; wloc[3] = e3*inv;
        }
        float w[16];
        #pragma unroll
        for (int j = 0; j < 4; j++) w[h*4 + j] = wloc[j];
        #pragma unroll
        for (int m = 1; m < 4; m++) {
            int oh = h ^ m;
            #pragma unroll
            for (int j = 0; j < 4; j++) w[oh*4 + j] = __shfl_xor(wloc[j], m);
        }

        const bf16x8* m3v = (const bf16x8*)(M3B + p*128);
        const bf16x8* t0  = (const bf16x8*)(O0 + p*512);
        const bf16x8* t1  = (const bf16x8*)(O1 + ta*512);
        const bf16x8* t2  = (const bf16x8*)(O2 + tb*512);
        const bf16x8* t3  = (const bf16x8*)O3g;
        #pragma unroll
        for (int jj = 0; jj < 4; jj++) {
            int c8 = h*4 + jj;
            bf16x8 mv = m3v[c8];
            float v[8];
            #pragma unroll
            for (int e = 0; e < 8; e++) v[e] = (float)mv[e];
            #pragma unroll
            for (int hh = 0; hh < 4; hh++) {
                int o8 = hh*16 + c8;
                bf16x8 e0 = t0[o8], e1 = t1[o8], e2 = t2[o8], e3 = t3[o8];
                float w0 = w[hh*4+0], w1 = w[hh*4+1], w2 = w[hh*4+2], w3 = w[hh*4+3];
                #pragma unroll
                for (int e = 0; e < 8; e++)
                    v[e] += w0*(float)e0[e] + w1*(float)e1[e] + w2*(float)e2[e] + w3*(float)e3[e];
            }
            bf16x8 st;
            #pragma unroll
            for (int e = 0; e < 8; e++) st[e] = (__bf16)v[e];
            *(bf16x8*)(sX3 + row*256 + ((c8*16) ^ ((row&7)<<4))) = st;
        }
    }

    // A-fragments (wave-private rows; same-wave DS ops are in-order)
    bf16x8 a[2][4];
    #pragma unroll
    for (int rg = 0; rg < 2; rg++) {
        int arow = wv*32 + rg*16 + lr;
        #pragma unroll
        for (int kb = 0; kb < 4; kb++)
            a[rg][kb] = *(const bf16x8*)(sX3 + arow*256 + ((kb*64 + quad*16) ^ ((arow&7)<<4)));
    }
    asm volatile("s_waitcnt lgkmcnt(0)" ::: "memory");
    __builtin_amdgcn_sched_barrier(0);

    // stage chunk-0 W1 into buf0 [0,8192) — disjoint from live x3 region
    {
        float4* d1 = (float4*)smem;
        d1[tid] = v0; d1[tid + 256] = v1;
    }
    __syncthreads();                       // barrier#1: x3 fully consumed
    {
        float4* d2 = (float4*)(smem + 16384);
        d2[tid] = v2; d2[tid + 256] = v3;  // W2 buf0 overlays dead x3
    }
    __syncthreads();                       // barrier#2: chunk 0 staged

    char* sPanH = smem + 32768 + wv*2560;  // H panel: 32 x 40 bf16, wave-private

    f32x4 acc2[2][8];
    #pragma unroll
    for (int rg = 0; rg < 2; rg++)
        #pragma unroll
        for (int i = 0; i < 8; i++) acc2[rg][i] = (f32x4){0.f, 0.f, 0.f, 0.f};

    for (int cc = 0; cc < 16; cc++) {
        int p = cc & 1;
        char* w1b = smem + p*8192;
        char* w2b = smem + 16384 + p*8192;
        if (cc < 15) {  // issue next chunk's loads — latency hides under compute
            const float4* g1 = (const float4*)(gW1 + (cc+1)*8192);
            const float4* g2 = (const float4*)(gW2 + (cc+1)*8192);
            v0 = g1[tid]; v1 = g1[tid + 256]; v2 = g2[tid]; v3 = g2[tid + 256];
        }
        // MLP1: 2 col-groups; each W1 fragment feeds both row-groups
        #pragma unroll
        for (int nbl = 0; nbl < 2; nbl++) {
            float bv = b1[cc*32 + nbl*16 + lr];
            f32x4 accA = (f32x4){bv, bv, bv, bv};
            f32x4 accB = (f32x4){bv, bv, bv, bv};
            #pragma unroll
            for (int kb = 0; kb < 4; kb++) {
                bf16x8 w1 = *(const bf16x8*)(w1b + ((nbl*4 + kb)*64 + l)*16);
                accA = __builtin_amdgcn_mfma_f32_16x16x32_bf16(a[0][kb], w1, accA, 0, 0, 0);
                accB = __builtin_amdgcn_mfma_f32_16x16x32_bf16(a[1][kb], w1, accB, 0, 0, 0);
            }
            #pragma unroll
            for (int r = 0; r < 4; r++) {
                *(__bf16*)(sPanH + (((quad*4 + r)*40)      + nbl*16 + lr)*2) = (__bf16)fmaxf(accA[r], 0.f);
                *(__bf16*)(sPanH + (((16 + quad*4 + r)*40) + nbl*16 + lr)*2) = (__bf16)fmaxf(accB[r], 0.f);
            }
        }
        // MLP2 partial: each W2 fragment feeds both row-groups
        {
            bf16x8 h0 = *(const bf16x8*)(sPanH + ((lr)*40      + quad*8)*2);
            bf16x8 h1 = *(const bf16x8*)(sPanH + ((16 + lr)*40 + quad*8)*2);
            #pragma unroll
            for (int nb2 = 0; nb2 < 8; nb2++) {
                bf16x8 w2 = *(const bf16x8*)(w2b + (nb2*64 + l)*16);
                acc2[0][nb2] = __builtin_amdgcn_mfma_f32_16x16x32_bf16(h0, w2, acc2[0][nb2], 0, 0, 0);
                acc2[1][nb2] = __builtin_amdgcn_mfma_f32_16x16x32_bf16(h1, w2, acc2[1][nb2], 0, 0, 0);
            }
        }
        if (cc < 15) {  // write next chunk into the other buffer, then ONE barrier
            float4* d1 = (float4*)(smem + (p^1)*8192);
            float4* d2 = (float4*)(smem + 16384 + (p^1)*8192);
            d1[tid] = v0; d1[tid + 256] = v1; d2[tid] = v2; d2[tid + 256] = v3;
        }
        __syncthreads();
    }

    // residual via identity-matrix MFMA
    #pragma unroll
    for (int nb2 = 0; nb2 < 8; nb2++) {
        int kb = nb2 >> 1;
        bf16x8 bi;
        #pragma unroll
        for (int j = 0; j < 8; j++)
            bi[j] = (kb*32 + quad*8 + j == nb2*16 + lr) ? (__bf16)1.0f : (__bf16)0.0f;
        acc2[0][nb2] = __builtin_amdgcn_mfma_f32_16x16x32_bf16(a[0][kb], bi, acc2[0][nb2], 0, 0, 0);
        acc2[1][nb2] = __builtin_amdgcn_mfma_f32_16x16x32_bf16(a[1][kb], bi, acc2[1][nb2], 0, 0, 0);
    }

    // x'' = acc2 + b2 -> swizzled epilogue panel at [0,32768), wave-private rows
    #pragma unroll
    for (int nb2 = 0; nb2 < 8; nb2++) {
        int n = nb2*16 + lr;
        float bv = b2[n];
        #pragma unroll
        for (int rg = 0; rg < 2; rg++)
            #pragma unroll
            for (int r = 0; r < 4; r++) {
                float v = acc2[rg][nb2][r] + bv;
                int row = wv*32 + rg*16 + quad*4 + r;
                *(__bf16*)(smem + row*256 + ((n*2) ^ ((row&7)<<4))) = (__bf16)v;
            }
    }
    asm volatile("s_waitcnt lgkmcnt(0)" ::: "memory");
    __builtin_amdgcn_sched_barrier(0);
    bf16x8 au[2][4];
    #pragma unroll
    for (int rg = 0; rg < 2; rg++) {
        int arow = wv*32 + rg*16 + lr;
        #pragma unroll
        for (int kb = 0; kb < 4; kb++)
            au[rg][kb] = *(const bf16x8*)(smem + arow*256 + ((kb*64 + quad*16) ^ ((arow&7)<<4)));
    }

    // unembed: WU staged through [32768,49152) in 3 passes (nt 0-3, 4-7, 8-9)
    const char* gWU = (const char*)WUf;
    char* sWU = smem + 32768;
    #pragma unroll
    for (int q = 0; q < 3; q++) {
        __syncthreads();                   // previous pass fully read / H dead
        if (q < 2) {
            const float4* g = (const float4*)(gWU + q*16384);
            float4 u0 = g[tid], u1 = g[tid+256], u2 = g[tid+512], u3 = g[tid+768];
            float4* dd = (float4*)sWU;
            dd[tid] = u0; dd[tid+256] = u1; dd[tid+512] = u2; dd[tid+768] = u3;
        } else {
            const float4* g = (const float4*)(gWU + 32768);
            float4 u0 = g[tid], u1 = g[tid+256];
            float4* dd = (float4*)sWU;
            dd[tid] = u0; dd[tid+256] = u1;
        }
        __syncthreads();
        int ntn = (q < 2) ? 4 : 2;
        for (int ntl = 0; ntl < ntn; ntl++) {
            int nt = q*4 + ntl;
            int n = nt*16 + lr;
            float bv = (n < 150) ? bun[n] : 0.f;
            f32x4 accU0 = (f32x4){bv, bv, bv, bv};
            f32x4 accU1 = (f32x4){bv, bv, bv, bv};
            #pragma unroll
            for (int kb = 0; kb < 4; kb++) {
                bf16x8 wu = *(const bf16x8*)(sWU + ((ntl*4 + kb)*64 + l)*16);
                accU0 = __builtin_amdgcn_mfma_f32_16x16x32_bf16(au[0][kb], wu, accU0, 0, 0, 0);
                accU1 = __builtin_amdgcn_mfma_f32_16x16x32_bf16(au[1][kb], wu, accU1, 0, 0, 0);
            }
            if (n < 150) {
                #pragma unroll
                for (int r = 0; r < 4; r++) {
                    out[(tbase +      quad*4 + r)*150 + n] = accU0[r];
                    out[(tbase + 16 + quad*4 + r)*150 + n] = accU1[r];
                }
            }
        }
    }
}

// ============================ launcher ======================================
extern "C" void kernel_launch(void* const* d_in, const int* in_sizes, int n_in,
                              void* d_out, int out_size, void* d_ws, size_t ws_size,
                              hipStream_t stream) {
    const int*   p_val = (const int*)d_in[0];
    const int*   a_tok = (const int*)d_in[1];
    const int*   b_tok = (const int*)d_in[2];
    const float* tok   = (const float*)d_in[3];
    const float* pos   = (const float*)d_in[4];
    const float* W_mem = (const float*)d_in[5];
    const float* b_mem = (const float*)d_in[6];
    const float* W_sur = (const float*)d_in[7];
    const float* b_sur = (const float*)d_in[8];
    const float* W_m2r = (const float*)d_in[9];
    const float* b_m2r = (const float*)d_in[10];
    const float* W_Q   = (const float*)d_in[11];
    const float* W_K   = (const float*)d_in[12];
    const float* W_V   = (const float*)d_in[13];
    const float* W_O   = (const float*)d_in[14];
    const float* W1    = (const float*)d_in[15];
    const float* b1    = (const float*)d_in[16];
    const float* W2    = (const float*)d_in[17];
    const float* b2    = (const float*)d_in[18];
    const float* WU    = (const float*)d_in[19];
    const float* bun   = (const float*)d_in[20];
    float* out = (float*)d_out;

    float* ws = (float*)d_ws;
    float* memvec = ws + OFF_MEMVEC;
    float* x3base = ws + OFF_X3BASE;
    float* KE     = ws + OFF_KE;
    float* KP     = ws + OFF_KP;
    float* SC     = ws + OFF_SC;
    __bf16* O0    = (__bf16*)(ws + OFF_O0);
    __bf16* O1    = (__bf16*)(ws + OFF_O1);
    __bf16* O2    = (__bf16*)(ws + OFF_O2);
    __bf16* O3    = (__bf16*)(ws + OFF_O3);
    __bf16* M3B   = (__bf16*)(ws + OFF_M3B);
    __bf16* W1f   = (__bf16*)(ws + OFF_W1F);
    __bf16* W2f   = (__bf16*)(ws + OFF_W2F);
    __bf16* WUf   = (__bf16*)(ws + OFF_WUF);

    k_P1a<<<307, 256, 0, stream>>>(tok, pos, W_mem, b_mem, W_sur, b_sur, W_m2r, b_m2r,
                                   W_K, memvec, x3base, KE, KP);
    k_P2x<<<825, 256, 0, stream>>>(memvec, x3base, W_Q, W_V, W_O, KE, KP,
                                   tok, pos, W1, W2, WU,
                                   SC, M3B, O0, O1, O2, O3, W1f, W2f, WUf);
    k_fused<<<NBATCH/128, 256, 0, stream>>>(p_val, a_tok, b_tok, SC, O0, O1, O2, O3, M3B,
                                            W1f, W2f, WUf, b1, b2, bun, out);
}

// Round 7
// 173.038 us; speedup vs baseline: 1.0949x; 1.0426x over previous
//
#include <hip/hip_runtime.h>

#define D      128
#define DM     64
#define DMLP   512
#define PMAX   150
#define VOC    152
#define EQT    151
#define NBATCH 65536

typedef __attribute__((ext_vector_type(8))) __bf16 bf16x8;
typedef __attribute__((ext_vector_type(4))) float  f32x4;

__device__ __forceinline__ float silu_f(float x){ return x / (1.0f + expf(-x)); }

// ---- workspace layout (float-slot offsets) ----
#define OFF_MEMVEC 0        // 150*128 f32
#define OFF_X3BASE 19200    // 128 f32
#define OFF_KE     19328    // 152*128 f32
#define OFF_KP     38784    // 4*128 f32
#define OFF_SC     39296    // 150*624 f32
#define OFF_O0     132896   // 150*512 bf16
#define OFF_O1     171296   // 150*512 bf16
#define OFF_O2     209696   // 150*512 bf16
#define OFF_O3     248096   // 512 bf16
#define OFF_M3B    248352   // 150*128 bf16
#define OFF_W1F    257952   // 65536 bf16 frag-packed (chunk-contiguous)
#define OFF_W2F    290720   // 65536 bf16 frag-packed K-major (chunk-contiguous)
#define OFF_WUF    323488   // 20480 bf16

// ===== P1a: memvec + x3base + K tables (307 blocks x 256) ====================
__global__ void k_P1a(const float* __restrict__ tok, const float* __restrict__ pos,
                      const float* __restrict__ W_mem, const float* __restrict__ b_mem,
                      const float* __restrict__ W_sur, const float* __restrict__ b_sur,
                      const float* __restrict__ W_m2r, const float* __restrict__ b_m2r,
                      const float* __restrict__ W_K,
                      float* __restrict__ memvec, float* __restrict__ x3base,
                      float* __restrict__ KE, float* __restrict__ KP)
{
    int r = blockIdx.x, t = threadIdx.x;
    if (r < 150) {
        int p = r;
        __shared__ float sx0[D], sz[DM], sdiff[D], szu[DM];
        if (t < D) sx0[t] = tok[p*D + t] + pos[t];
        __syncthreads();
        if (t < DM) {
            float acc = b_mem[t];
            for (int d = 0; d < D; d++) acc += sx0[d] * W_mem[d*DM + t];
            sz[t] = silu_f(acc);
        }
        __syncthreads();
        if (t < D) {
            float acc = b_sur[t];
            for (int j = 0; j < DM; j++) acc += sz[j] * W_sur[j*D + t];
            sdiff[t] = sx0[t] - acc;
        }
        __syncthreads();
        if (t < DM) {
            float acc = 0.f;
            for (int d = 0; d < D; d++) acc += sdiff[d] * W_mem[d*DM + t];
            szu[t] = sz[t] + silu_f(acc);
        }
        __syncthreads();
        if (t < D) {
            float acc = b_m2r[t];
            for (int j = 0; j < DM; j++) acc += szu[j] * W_m2r[j*D + t];
            memvec[p*D + t] = acc;
        }
    } else if (r == 150) {
        if (t < D) x3base[t] = tok[EQT*D + t] + pos[3*D + t];
    } else {
        int idx = r - 151;
        const float* src = (idx < 152) ? (tok + idx*D) : (pos + (idx-152)*D);
        float*       dst = (idx < 152) ? (KE + idx*D)  : (KP + (idx-152)*D);
        __shared__ float s[D];
        if (t < D) s[t] = src[t];
        __syncthreads();
        if (t < D) {
            int h = t >> 5, k = t & 31;
            float acc = 0.f;
            for (int d = 0; d < D; d++) acc += s[d] * W_K[h*4096 + d*32 + k];
            dst[t] = acc;
        }
    }
}

// ===== P2x: SC/M3B (blocks 0-299) + O-tables + weight repack (blocks 300-824)
__global__ void k_P2x(const float* __restrict__ memvec, const float* __restrict__ x3base,
                      const float* __restrict__ W_Q, const float* __restrict__ W_V,
                      const float* __restrict__ W_O,
                      const float* __restrict__ KE, const float* __restrict__ KP,
                      const float* __restrict__ tok, const float* __restrict__ pos,
                      const float* __restrict__ W1, const float* __restrict__ W2,
                      const float* __restrict__ WU,
                      float* __restrict__ SC, __bf16* __restrict__ M3B,
                      __bf16* __restrict__ O0, __bf16* __restrict__ O1,
                      __bf16* __restrict__ O2, __bf16* __restrict__ O3,
                      __bf16* __restrict__ W1f, __bf16* __restrict__ W2f, __bf16* __restrict__ WUf)
{
    int r = blockIdx.x, t = threadIdx.x;
    if (r < 300) {
        int p = r >> 1, half = r & 1;
        __shared__ float sMem[D], sIn[D], sQ3[D], sMV[D];
        if (t < D) { float m = memvec[p*D + t]; sMem[t] = m; sIn[t] = m + x3base[t]; }
        __syncthreads();
        if (t < D) {
            int h = t >> 5, k = t & 31;
            float acc = 0.f;
            for (int d = 0; d < D; d++) acc += sIn[d] * W_Q[h*4096 + d*32 + k];
            sQ3[t] = acc;
        } else {
            int c = t - D; int h = c >> 5, k = c & 31;
            float acc = 0.f;
            for (int d = 0; d < D; d++) acc += sMem[d] * W_V[h*4096 + d*32 + k];
            sMV[c] = acc;
        }
        __syncthreads();
        const float scale = 0.17677669529663687f;
        for (int ii = t; ii < 312; ii += 256) {
            int i = half*312 + ii;
            int v = i >> 2, h = i & 3;
            const float4* qh = (const float4*)(sQ3 + h*32);
            float4 s4 = {0.f, 0.f, 0.f, 0.f};
            if (v < 152) {
                const float4* ke = (const float4*)(KE + v*D + h*32);
                #pragma unroll
                for (int k = 0; k < 8; k++) {
                    float4 q = qh[k], e = ke[k];
                    s4.x += q.x*e.x; s4.y += q.y*e.y; s4.z += q.z*e.z; s4.w += q.w*e.w;
                }
            } else if (v == 152 || v == 153) {
                const float4* ke = (const float4*)(KE + ((v==152)? p : EQT)*D + h*32);
                const float4* kp = (const float4*)(KP + ((v==152)? 0 : 3)*D + h*32);
                #pragma unroll
                for (int k = 0; k < 8; k++) {
                    float4 q = qh[k], e = ke[k], pp = kp[k];
                    s4.x += q.x*(e.x+pp.x); s4.y += q.y*(e.y+pp.y);
                    s4.z += q.z*(e.z+pp.z); s4.w += q.w*(e.w+pp.w);
                }
            } else {
                const float4* kp = (const float4*)(KP + ((v==154)?1:2)*D + h*32);
                #pragma unroll
                for (int k = 0; k < 8; k++) {
                    float4 q = qh[k], pp = kp[k];
                    s4.x += q.x*pp.x; s4.y += q.y*pp.y; s4.z += q.z*pp.z; s4.w += q.w*pp.w;
                }
            }
            SC[p*624 + i] = (s4.x + s4.y + s4.z + s4.w) * scale;
        }
        if (half == 0 && t < D) {
            float acc = sIn[t];
            for (int c = 0; c < D; c++) acc += sMV[c] * W_O[c*D + t];
            M3B[p*D + t] = (__bf16)acc;
        }
        return;
    }
    int rr = r - 300;
    if (rr < 451) {
        int idx = rr;
        int tt, v; __bf16* outp;
        if (idx < 150)      { tt = 0; v = idx;       outp = O0 + v*512; }
        else if (idx < 300) { tt = 1; v = idx - 150; outp = O1 + (idx-150)*512; }
        else if (idx < 450) { tt = 2; v = idx - 300; outp = O2 + (idx-300)*512; }
        else                { tt = 3; v = EQT;       outp = O3; }
        __shared__ float sTP[D], sv[D];
        if (t < D) sTP[t] = tok[v*D + t] + pos[tt*D + t];
        __syncthreads();
        if (t < D) {
            int h = t >> 5, k = t & 31;
            float acc = 0.f;
            for (int d = 0; d < D; d++) acc += sTP[d] * W_V[h*4096 + d*32 + k];
            sv[t] = acc;
        }
        __syncthreads();
        #pragma unroll
        for (int i = 0; i < 2; i++) {
            int c = t + i*256;
            int h = c >> 7, m = c & 127;
            float acc = 0.f;
            for (int k = 0; k < 32; k++) acc += sv[h*32 + k] * W_O[h*4096 + k*128 + m];
            outp[c] = (__bf16)acc;
        }
    } else if (rr < 483) {
        int f = (rr-451)*256 + t;                      // W1 128x512, f=(nbg*4+kb)*64+l
        int l = f & 63, kb = (f>>6) & 3, nb = f >> 8;
        int k0 = kb*32 + (l>>4)*8, n = nb*16 + (l&15);
        #pragma unroll
        for (int j = 0; j < 8; j++) W1f[f*8 + j] = (__bf16)W1[(k0+j)*DMLP + n];
    } else if (rr < 515) {
        int f = (rr-483)*256 + t;                      // W2 512x128, K-MAJOR: f=(kb*8+nb)*64+l
        int l = f & 63, g = f >> 6;
        int nb = g & 7, kb = g >> 3;
        int k0 = kb*32 + (l>>4)*8, n = nb*16 + (l&15);
        #pragma unroll
        for (int j = 0; j < 8; j++) W2f[f*8 + j] = (__bf16)W2[(k0+j)*D + n];
    } else {
        int f = (rr-515)*256 + t;                      // W_un 128x150 (N pad 160), f=(nt*4+kb)*64+l
        int l = f & 63, kb = (f>>6) & 3, nb = f >> 8;
        int k0 = kb*32 + (l>>4)*8, n = nb*16 + (l&15);
        #pragma unroll
        for (int j = 0; j < 8; j++) WUf[f*8 + j] = (__bf16)((n < 150) ? WU[(k0+j)*150 + n] : 0.f);
    }
}

// ===== FUSED v5: 64 samples/block + dbuf W + 1 barrier/chunk + 4 blk/CU =====
// 1024 blocks x 256 thr (4 waves), 16 rows/wave, 4 blocks/CU (16 waves/CU).
// Completes the factorial: R4 (4blk, 2-barrier) = 70 us; R6 (2blk, dbuf-1bar)
// = 70 us; R3 (2blk, 2-barrier) = 100 us -> this corner (4blk, dbuf-1bar).
// LDS (37888 B <= 40960 -> 4 blk/CU):
//   [0,8192)       W1 buf0   | [8192,16384)  W1 buf1
//   [16384,24576)  W2 buf0   | [24576,32768) W2 buf1
//   [32768,37888)  H panels, 1280 B/wave (16 x 40 bf16)
//   [16384,32768)  phase-A x3 panel (64 x 256 B swizzled) — dead before W2 staging
//   [0,16384)      epilogue x'' panel (64 x 256 B swizzled) — after chunk loop
//   [16384,32768)  WU staging passes — after chunk loop
// Biases from global (L1-hot, R6-proven). Per chunk: issue next loads ->
// MLP1+MLP2 -> ds_write other buf -> ONE barrier (T14 latency hiding).
__global__ __launch_bounds__(256, 4) void k_fused(
    const int* __restrict__ p_val, const int* __restrict__ a_tok, const int* __restrict__ b_tok,
    const float* __restrict__ SC, const __bf16* __restrict__ O0, const __bf16* __restrict__ O1,
    const __bf16* __restrict__ O2, const __bf16* __restrict__ O3g, const __bf16* __restrict__ M3B,
    const __bf16* __restrict__ W1f, const __bf16* __restrict__ W2f, const __bf16* __restrict__ WUf,
    const float* __restrict__ b1, const float* __restrict__ b2, const float* __restrict__ bun,
    float* __restrict__ out)
{
    __shared__ __align__(16) char smem[37888];
    char* sX3 = smem + 16384;              // x3 panel, 64 x 256 B, phase A only

    int tid = threadIdx.x;
    int wv = tid >> 6, l = tid & 63, lr = l & 15, quad = l >> 4;
    int tbase = blockIdx.x * 64 + wv * 16;

    const char* gW1 = (const char*)W1f;
    const char* gW2 = (const char*)W2f;

    // chunk-0 staging loads issued FIRST — in flight during the attention phase
    float4 v0, v1, v2, v3;
    {
        const float4* g1 = (const float4*)gW1;
        const float4* g2 = (const float4*)gW2;
        v0 = g1[tid]; v1 = g1[tid + 256]; v2 = g2[tid]; v3 = g2[tid + 256];
    }

    // ---------- phase A: attention; wave-private 16 rows (s = wv*16 + l>>2) ----
    {
        int s = tid >> 2, h = tid & 3;
        int gs = blockIdx.x * 64 + s;
        int p = p_val[gs], ta = a_tok[gs], tb = b_tok[gs];

        float wloc[4];
        {
            const float* SCp = SC + p*624;
            float sc0 = SCp[608 + h];
            float sc3 = SCp[612 + h];
            float sc1 = SCp[ta*4 + h] + SCp[616 + h];
            float sc2 = SCp[tb*4 + h] + SCp[620 + h];
            float mx = fmaxf(fmaxf(sc0, sc1), fmaxf(sc2, sc3));
            float e0 = expf(sc0-mx), e1 = expf(sc1-mx), e2 = expf(sc2-mx), e3 = expf(sc3-mx);
            float inv = 1.f / (e0 + e1 + e2 + e3);
            wloc[0] = e0*inv; wloc[1] = e1*inv; wloc[2] = e2*inv; wloc[3] = e3*inv;
        }
        float w[16];
        #pragma unroll
        for (int j = 0; j < 4; j++) w[h*4 + j] = wloc[j];
        #pragma unroll
        for (int m = 1; m < 4; m++) {
            int oh = h ^ m;
            #pragma unroll
            for (int j = 0; j < 4; j++) w[oh*4 + j] = __shfl_xor(wloc[j], m);
        }

        const bf16x8* m3v = (const bf16x8*)(M3B + p*128);
        const bf16x8* t0  = (const bf16x8*)(O0 + p*512);
        const bf16x8* t1  = (const bf16x8*)(O1 + ta*512);
        const bf16x8* t2  = (const bf16x8*)(O2 + tb*512);
        const bf16x8* t3  = (const bf16x8*)O3g;
        #pragma unroll
        for (int jj = 0; jj < 4; jj++) {
            int c8 = h*4 + jj;
            bf16x8 mv = m3v[c8];
            float v[8];
            #pragma unroll
            for (int e = 0; e < 8; e++) v[e] = (float)mv[e];
            #pragma unroll
            for (int hh = 0; hh < 4; hh++) {
                int o8 = hh*16 + c8;
                bf16x8 e0 = t0[o8], e1 = t1[o8], e2 = t2[o8], e3 = t3[o8];
                float w0 = w[hh*4+0], w1 = w[hh*4+1], w2 = w[hh*4+2], w3 = w[hh*4+3];
                #pragma unroll
                for (int e = 0; e < 8; e++)
                    v[e] += w0*(float)e0[e] + w1*(float)e1[e] + w2*(float)e2[e] + w3*(float)e3[e];
            }
            bf16x8 st;
            #pragma unroll
            for (int e = 0; e < 8; e++) st[e] = (__bf16)v[e];
            *(bf16x8*)(sX3 + s*256 + ((c8*16) ^ ((s&7)<<4))) = st;
        }
    }
    asm volatile("s_waitcnt lgkmcnt(0)" ::: "memory");
    __builtin_amdgcn_sched_barrier(0);

    // A-fragments from wave-private rows (same-wave write->read, lgkm-ordered)
    bf16x8 a[4];
    {
        int arow = wv*16 + lr;                         // arow&7 == lr&7
        #pragma unroll
        for (int kb = 0; kb < 4; kb++)
            a[kb] = *(const bf16x8*)(sX3 + arow*256 + ((kb*64 + quad*16) ^ ((lr&7)<<4)));
    }
    // W1 buf0 [0,8192) is disjoint from x3 — stage immediately
    {
        float4* d1 = (float4*)smem;
        d1[tid] = v0; d1[tid + 256] = v1;
    }
    __syncthreads();                       // all waves done with x3 region
    {
        float4* d2 = (float4*)(smem + 16384);          // W2 buf0 overlays dead x3
        d2[tid] = v2; d2[tid + 256] = v3;
    }
    __syncthreads();                       // chunk 0 fully staged

    char* sPanH = smem + 32768 + wv*1280;  // H panel: 16 x 40 bf16, wave-private

    f32x4 acc2[8];
    #pragma unroll
    for (int i = 0; i < 8; i++) acc2[i] = (f32x4){0.f, 0.f, 0.f, 0.f};

    for (int cc = 0; cc < 16; cc++) {
        int p = cc & 1;
        char* w1b = smem + p*8192;
        char* w2b = smem + 16384 + p*8192;
        if (cc < 15) {  // issue next chunk's loads — latency hides under compute
            const float4* g1 = (const float4*)(gW1 + (cc+1)*8192);
            const float4* g2 = (const float4*)(gW2 + (cc+1)*8192);
            v0 = g1[tid]; v1 = g1[tid + 256]; v2 = g2[tid]; v3 = g2[tid + 256];
        }
        // MLP1: 2 col-groups of 16
        #pragma unroll
        for (int nbl = 0; nbl < 2; nbl++) {
            float bv = b1[cc*32 + nbl*16 + lr];
            f32x4 acc = (f32x4){bv, bv, bv, bv};
            #pragma unroll
            for (int kb = 0; kb < 4; kb++) {
                bf16x8 w1 = *(const bf16x8*)(w1b + ((nbl*4 + kb)*64 + l)*16);
                acc = __builtin_amdgcn_mfma_f32_16x16x32_bf16(a[kb], w1, acc, 0, 0, 0);
            }
            #pragma unroll
            for (int r = 0; r < 4; r++)
                *(__bf16*)(sPanH + (((quad*4 + r)*40) + nbl*16 + lr)*2) = (__bf16)fmaxf(acc[r], 0.f);
        }
        asm volatile("s_waitcnt lgkmcnt(0)" ::: "memory");
        __builtin_amdgcn_sched_barrier(0);
        // MLP2 partial: this chunk's 32-wide K block
        {
            bf16x8 h = *(const bf16x8*)(sPanH + (lr*40 + quad*8)*2);
            #pragma unroll
            for (int nb2 = 0; nb2 < 8; nb2++) {
                bf16x8 w2 = *(const bf16x8*)(w2b + (nb2*64 + l)*16);
                acc2[nb2] = __builtin_amdgcn_mfma_f32_16x16x32_bf16(h, w2, acc2[nb2], 0, 0, 0);
            }
        }
        if (cc < 15) {  // write next chunk into the other buffers (safe: consumed
                        // at cc-1 and barrier-crossed), then ONE barrier
            float4* d1 = (float4*)(smem + (p^1)*8192);
            float4* d2 = (float4*)(smem + 16384 + (p^1)*8192);
            d1[tid] = v0; d1[tid + 256] = v1; d2[tid] = v2; d2[tid + 256] = v3;
        }
        __syncthreads();
    }

    // residual via identity-matrix MFMA
    #pragma unroll
    for (int nb2 = 0; nb2 < 8; nb2++) {
        int kb = nb2 >> 1;
        bf16x8 bi;
        #pragma unroll
        for (int j = 0; j < 8; j++)
            bi[j] = (kb*32 + quad*8 + j == nb2*16 + lr) ? (__bf16)1.0f : (__bf16)0.0f;
        acc2[nb2] = __builtin_amdgcn_mfma_f32_16x16x32_bf16(a[kb], bi, acc2[nb2], 0, 0, 0);
    }

    // x'' = acc2 + b2 -> swizzled epilogue panel at [0,16384), wave-private rows
    #pragma unroll
    for (int nb2 = 0; nb2 < 8; nb2++) {
        int n = nb2*16 + lr;
        float bv = b2[n];
        #pragma unroll
        for (int r = 0; r < 4; r++) {
            float v = acc2[nb2][r] + bv;
            int row = wv*16 + quad*4 + r;
            *(__bf16*)(smem + row*256 + ((n*2) ^ ((row&7)<<4))) = (__bf16)v;
        }
    }
    asm volatile("s_waitcnt lgkmcnt(0)" ::: "memory");
    __builtin_amdgcn_sched_barrier(0);
    bf16x8 au[4];
    {
        int arow = wv*16 + lr;
        #pragma unroll
        for (int kb = 0; kb < 4; kb++)
            au[kb] = *(const bf16x8*)(smem + arow*256 + ((kb*64 + quad*16) ^ ((lr&7)<<4)));
    }

    // unembed: WU staged through [16384,32768) in 3 passes (nt 0-3, 4-7, 8-9)
    const char* gWU = (const char*)WUf;
    char* sWU = smem + 16384;
    #pragma unroll
    for (int q = 0; q < 3; q++) {
        __syncthreads();                   // previous pass fully read
        if (q < 2) {
            const float4* g = (const float4*)(gWU + q*16384);
            float4 u0 = g[tid], u1 = g[tid+256], u2 = g[tid+512], u3 = g[tid+768];
            float4* dd = (float4*)sWU;
            dd[tid] = u0; dd[tid+256] = u1; dd[tid+512] = u2; dd[tid+768] = u3;
        } else {
            const float4* g = (const float4*)(gWU + 32768);
            float4 u0 = g[tid], u1 = g[tid+256];
            float4* dd = (float4*)sWU;
            dd[tid] = u0; dd[tid+256] = u1;
        }
        __syncthreads();
        int ntn = (q < 2) ? 4 : 2;
        for (int ntl = 0; ntl < ntn; ntl++) {
            int nt = q*4 + ntl;
            int n = nt*16 + lr;
            float bv = (n < 150) ? bun[n] : 0.f;
            f32x4 acc = (f32x4){bv, bv, bv, bv};
            #pragma unroll
            for (int kb = 0; kb < 4; kb++) {
                bf16x8 wu = *(const bf16x8*)(sWU + ((ntl*4 + kb)*64 + l)*16);
                acc = __builtin_amdgcn_mfma_f32_16x16x32_bf16(au[kb], wu, acc, 0, 0, 0);
            }
            if (n < 150) {
                #pragma unroll
                for (int r = 0; r < 4; r++) {
                    int rowg = tbase + quad*4 + r;
                    out[rowg*150 + n] = acc[r];
                }
            }
        }
    }
}

// ============================ launcher ======================================
extern "C" void kernel_launch(void* const* d_in, const int* in_sizes, int n_in,
                              void* d_out, int out_size, void* d_ws, size_t ws_size,
                              hipStream_t stream) {
    const int*   p_val = (const int*)d_in[0];
    const int*   a_tok = (const int*)d_in[1];
    const int*   b_tok = (const int*)d_in[2];
    const float* tok   = (const float*)d_in[3];
    const float* pos   = (const float*)d_in[4];
    const float* W_mem = (const float*)d_in[5];
    const float* b_mem = (const float*)d_in[6];
    const float* W_sur = (const float*)d_in[7];
    const float* b_sur = (const float*)d_in[8];
    const float* W_m2r = (const float*)d_in[9];
    const float* b_m2r = (const float*)d_in[10];
    const float* W_Q   = (const float*)d_in[11];
    const float* W_K   = (const float*)d_in[12];
    const float* W_V   = (const float*)d_in[13];
    const float* W_O   = (const float*)d_in[14];
    const float* W1    = (const float*)d_in[15];
    const float* b1    = (const float*)d_in[16];
    const float* W2    = (const float*)d_in[17];
    const float* b2    = (const float*)d_in[18];
    const float* WU    = (const float*)d_in[19];
    const float* bun   = (const float*)d_in[20];
    float* out = (float*)d_out;

    float* ws = (float*)d_ws;
    float* memvec = ws + OFF_MEMVEC;
    float* x3base = ws + OFF_X3BASE;
    float* KE     = ws + OFF_KE;
    float* KP     = ws + OFF_KP;
    float* SC     = ws + OFF_SC;
    __bf16* O0    = (__bf16*)(ws + OFF_O0);
    __bf16* O1    = (__bf16*)(ws + OFF_O1);
    __bf16* O2    = (__bf16*)(ws + OFF_O2);
    __bf16* O3    = (__bf16*)(ws + OFF_O3);
    __bf16* M3B   = (__bf16*)(ws + OFF_M3B);
    __bf16* W1f   = (__bf16*)(ws + OFF_W1F);
    __bf16* W2f   = (__bf16*)(ws + OFF_W2F);
    __bf16* WUf   = (__bf16*)(ws + OFF_WUF);

    k_P1a<<<307, 256, 0, stream>>>(tok, pos, W_mem, b_mem, W_sur, b_sur, W_m2r, b_m2r,
                                   W_K, memvec, x3base, KE, KP);
    k_P2x<<<825, 256, 0, stream>>>(memvec, x3base, W_Q, W_V, W_O, KE, KP,
                                   tok, pos, W1, W2, WU,
                                   SC, M3B, O0, O1, O2, O3, W1f, W2f, WUf);
    k_fused<<<NBATCH/64, 256, 0, stream>>>(p_val, a_tok, b_tok, SC, O0, O1, O2, O3, M3B,
                                           W1f, W2f, WUf, b1, b2, bun, out);
}

// Round 8
// 169.382 us; speedup vs baseline: 1.1185x; 1.0216x over previous
//
#include <hip/hip_runtime.h>

#define D      128
#define DM     64
#define DMLP   512
#define PMAX   150
#define VOC    152
#define EQT    151
#define NBATCH 65536

typedef __attribute__((ext_vector_type(8))) __bf16 bf16x8;
typedef __attribute__((ext_vector_type(4))) float  f32x4;

__device__ __forceinline__ float silu_f(float x){ return x / (1.0f + expf(-x)); }

// async global->LDS DMA, 16B per lane; LDS dest = wave-uniform base + lane*16
__device__ __forceinline__ void gl_lds16(const void* g, void* l) {
    __builtin_amdgcn_global_load_lds(
        (const __attribute__((address_space(1))) void*)g,
        (__attribute__((address_space(3))) void*)l, 16, 0, 0);
}

// ---- workspace layout (float-slot offsets) ----
#define OFF_MEMVEC 0        // 150*128 f32
#define OFF_X3BASE 19200    // 128 f32
#define OFF_KE     19328    // 152*128 f32
#define OFF_KP     38784    // 4*128 f32
#define OFF_SC     39296    // 150*624 f32
#define OFF_O0     132896   // 150*512 bf16
#define OFF_O1     171296   // 150*512 bf16
#define OFF_O2     209696   // 150*512 bf16
#define OFF_O3     248096   // 512 bf16
#define OFF_M3B    248352   // 150*128 bf16
#define OFF_W1F    257952   // 65536 bf16 frag-packed (chunk-contiguous)
#define OFF_W2F    290720   // 65536 bf16 frag-packed K-major (chunk-contiguous)
#define OFF_WUF    323488   // 20480 bf16

// ===== P1a: memvec + x3base + K tables (307 blocks x 256) ====================
// Matvecs K-split across all 256 threads (serial length 384->128 for memvec,
// 128->64 for KE) — these blocks were latency-bound on serial k-loops.
__global__ void k_P1a(const float* __restrict__ tok, const float* __restrict__ pos,
                      const float* __restrict__ W_mem, const float* __restrict__ b_mem,
                      const float* __restrict__ W_sur, const float* __restrict__ b_sur,
                      const float* __restrict__ W_m2r, const float* __restrict__ b_m2r,
                      const float* __restrict__ W_K,
                      float* __restrict__ memvec, float* __restrict__ x3base,
                      float* __restrict__ KE, float* __restrict__ KP)
{
    int r = blockIdx.x, t = threadIdx.x;
    if (r < 150) {
        int p = r;
        __shared__ float sx0[D], sz[DM], sdiff[D], szu[DM], red4[4][DM], red2[2][D];
        if (t < D) sx0[t] = tok[p*D + t] + pos[t];
        __syncthreads();
        {   // z partials: 4-way K split over 128
            int out = t & 63, seg = t >> 6, k0 = seg*32;
            float acc = 0.f;
            for (int k = 0; k < 32; k++) acc += sx0[k0+k] * W_mem[(k0+k)*DM + out];
            red4[seg][out] = acc;
        }
        __syncthreads();
        if (t < DM) sz[t] = silu_f(b_mem[t] + red4[0][t] + red4[1][t] + red4[2][t] + red4[3][t]);
        __syncthreads();
        {   // pred partials: 2-way K split over 64
            int out = t & 127, seg = t >> 7, j0 = seg*32;
            float acc = 0.f;
            for (int j = 0; j < 32; j++) acc += sz[j0+j] * W_sur[(j0+j)*D + out];
            red2[seg][out] = acc;
        }
        __syncthreads();
        if (t < D) sdiff[t] = sx0[t] - (b_sur[t] + red2[0][t] + red2[1][t]);
        __syncthreads();
        {   // upd partials
            int out = t & 63, seg = t >> 6, k0 = seg*32;
            float acc = 0.f;
            for (int k = 0; k < 32; k++) acc += sdiff[k0+k] * W_mem[(k0+k)*DM + out];
            red4[seg][out] = acc;
        }
        __syncthreads();
        if (t < DM) szu[t] = sz[t] + silu_f(red4[0][t] + red4[1][t] + red4[2][t] + red4[3][t]);
        __syncthreads();
        {   // mem partials
            int out = t & 127, seg = t >> 7, j0 = seg*32;
            float acc = 0.f;
            for (int j = 0; j < 32; j++) acc += szu[j0+j] * W_m2r[(j0+j)*D + out];
            red2[seg][out] = acc;
        }
        __syncthreads();
        if (t < D) memvec[p*D + t] = b_m2r[t] + red2[0][t] + red2[1][t];
    } else if (r == 150) {
        if (t < D) x3base[t] = tok[EQT*D + t] + pos[3*D + t];
    } else {
        int idx = r - 151;
        const float* src = (idx < 152) ? (tok + idx*D) : (pos + (idx-152)*D);
        float*       dst = (idx < 152) ? (KE + idx*D)  : (KP + (idx-152)*D);
        __shared__ float s[D], red2[2][D];
        if (t < D) s[t] = src[t];
        __syncthreads();
        {
            int out = t & 127, seg = t >> 7, h = out >> 5, kk = out & 31, d0 = seg*64;
            float acc = 0.f;
            for (int d = 0; d < 64; d++) acc += s[d0+d] * W_K[h*4096 + (d0+d)*32 + kk];
            red2[seg][out] = acc;
        }
        __syncthreads();
        if (t < D) dst[t] = red2[0][t] + red2[1][t];
    }
}

// ===== P2x: SC/M3B (blocks 0-299) + O-tables + weight repack (blocks 300-824)
__global__ void k_P2x(const float* __restrict__ memvec, const float* __restrict__ x3base,
                      const float* __restrict__ W_Q, const float* __restrict__ W_V,
                      const float* __restrict__ W_O,
                      const float* __restrict__ KE, const float* __restrict__ KP,
                      const float* __restrict__ tok, const float* __restrict__ pos,
                      const float* __restrict__ W1, const float* __restrict__ W2,
                      const float* __restrict__ WU,
                      float* __restrict__ SC, __bf16* __restrict__ M3B,
                      __bf16* __restrict__ O0, __bf16* __restrict__ O1,
                      __bf16* __restrict__ O2, __bf16* __restrict__ O3,
                      __bf16* __restrict__ W1f, __bf16* __restrict__ W2f, __bf16* __restrict__ WUf)
{
    int r = blockIdx.x, t = threadIdx.x;
    if (r < 300) {
        int p = r >> 1, half = r & 1;
        __shared__ float sMem[D], sIn[D], sQ3[D], sMV[D], redM[2][D];
        if (t < D) { float m = memvec[p*D + t]; sMem[t] = m; sIn[t] = m + x3base[t]; }
        __syncthreads();
        if (t < D) {
            int h = t >> 5, k = t & 31;
            float acc = 0.f;
            for (int d = 0; d < D; d++) acc += sIn[d] * W_Q[h*4096 + d*32 + k];
            sQ3[t] = acc;
        } else {
            int c = t - D; int h = c >> 5, k = c & 31;
            float acc = 0.f;
            for (int d = 0; d < D; d++) acc += sMem[d] * W_V[h*4096 + d*32 + k];
            sMV[c] = acc;
        }
        __syncthreads();
        const float scale = 0.17677669529663687f;
        for (int ii = t; ii < 312; ii += 256) {
            int i = half*312 + ii;
            int v = i >> 2, h = i & 3;
            const float4* qh = (const float4*)(sQ3 + h*32);
            float4 s4 = {0.f, 0.f, 0.f, 0.f};
            if (v < 152) {
                const float4* ke = (const float4*)(KE + v*D + h*32);
                #pragma unroll
                for (int k = 0; k < 8; k++) {
                    float4 q = qh[k], e = ke[k];
                    s4.x += q.x*e.x; s4.y += q.y*e.y; s4.z += q.z*e.z; s4.w += q.w*e.w;
                }
            } else if (v == 152 || v == 153) {
                const float4* ke = (const float4*)(KE + ((v==152)? p : EQT)*D + h*32);
                const float4* kp = (const float4*)(KP + ((v==152)? 0 : 3)*D + h*32);
                #pragma unroll
                for (int k = 0; k < 8; k++) {
                    float4 q = qh[k], e = ke[k], pp = kp[k];
                    s4.x += q.x*(e.x+pp.x); s4.y += q.y*(e.y+pp.y);
                    s4.z += q.z*(e.z+pp.z); s4.w += q.w*(e.w+pp.w);
                }
            } else {
                const float4* kp = (const float4*)(KP + ((v==154)?1:2)*D + h*32);
                #pragma unroll
                for (int k = 0; k < 8; k++) {
                    float4 q = qh[k], pp = kp[k];
                    s4.x += q.x*pp.x; s4.y += q.y*pp.y; s4.z += q.z*pp.z; s4.w += q.w*pp.w;
                }
            }
            SC[p*624 + i] = (s4.x + s4.y + s4.z + s4.w) * scale;
        }
        if (half == 0) {
            {   // M3B: 2-way K split over the 128 attn channels
                int out = t & 127, seg = t >> 7, c0 = seg*64;
                float acc = 0.f;
                for (int c = 0; c < 64; c++) acc += sMV[c0+c] * W_O[(c0+c)*D + out];
                redM[seg][out] = acc;
            }
            __syncthreads();
            if (t < D) M3B[p*D + t] = (__bf16)(sIn[t] + redM[0][t] + redM[1][t]);
        }
        return;
    }
    int rr = r - 300;
    if (rr < 451) {
        int idx = rr;
        int tt, v; __bf16* outp;
        if (idx < 150)      { tt = 0; v = idx;       outp = O0 + v*512; }
        else if (idx < 300) { tt = 1; v = idx - 150; outp = O1 + (idx-150)*512; }
        else if (idx < 450) { tt = 2; v = idx - 300; outp = O2 + (idx-300)*512; }
        else                { tt = 3; v = EQT;       outp = O3; }
        __shared__ float sTP[D], sv[D], red2[2][D];
        if (t < D) sTP[t] = tok[v*D + t] + pos[tt*D + t];
        __syncthreads();
        {   // sv: 2-way K split
            int out = t & 127, seg = t >> 7, h = out >> 5, kk = out & 31, d0 = seg*64;
            float acc = 0.f;
            for (int d = 0; d < 64; d++) acc += sTP[d0+d] * W_V[h*4096 + (d0+d)*32 + kk];
            red2[seg][out] = acc;
        }
        __syncthreads();
        if (t < D) sv[t] = red2[0][t] + red2[1][t];
        __syncthreads();
        #pragma unroll
        for (int i = 0; i < 2; i++) {
            int c = t + i*256;
            int h = c >> 7, m = c & 127;
            float acc = 0.f;
            for (int k = 0; k < 32; k++) acc += sv[h*32 + k] * W_O[h*4096 + k*128 + m];
            outp[c] = (__bf16)acc;
        }
    } else if (rr < 483) {
        int f = (rr-451)*256 + t;                      // W1 128x512, f=(nbg*4+kb)*64+l
        int l = f & 63, kb = (f>>6) & 3, nb = f >> 8;
        int k0 = kb*32 + (l>>4)*8, n = nb*16 + (l&15);
        #pragma unroll
        for (int j = 0; j < 8; j++) W1f[f*8 + j] = (__bf16)W1[(k0+j)*DMLP + n];
    } else if (rr < 515) {
        int f = (rr-483)*256 + t;                      // W2 512x128, K-MAJOR: f=(kb*8+nb)*64+l
        int l = f & 63, g = f >> 6;
        int nb = g & 7, kb = g >> 3;
        int k0 = kb*32 + (l>>4)*8, n = nb*16 + (l&15);
        #pragma unroll
        for (int j = 0; j < 8; j++) W2f[f*8 + j] = (__bf16)W2[(k0+j)*D + n];
    } else {
        int f = (rr-515)*256 + t;                      // W_un 128x150 (N pad 160), f=(nt*4+kb)*64+l
        int l = f & 63, kb = (f>>6) & 3, nb = f >> 8;
        int k0 = kb*32 + (l>>4)*8, n = nb*16 + (l&15);
        #pragma unroll
        for (int j = 0; j < 8; j++) WUf[f*8 + j] = (__bf16)((n < 150) ? WU[(k0+j)*150 + n] : 0.f);
    }
}

// ===== FUSED v6: R7 geometry + global_load_lds staging =======================
// 1024 blocks x 256 thr (4 waves), 16 rows/wave, 4 blocks/CU.
// LDS (39936 B <= 40960 -> 4 blk/CU):
//   [0,8192)       W1 buf0   | [8192,16384)  W1 buf1
//   [16384,24576)  W2 buf0   | [24576,32768) W2 buf1
//   [32768,37888)  H panels, 1280 B/wave (16 x 40 bf16)
//   [37888,39936)  sB1: b1 bias (512 f32) — LDS so in-loop bias reads are
//                  lgkm-domain and never force an in-order vmcnt retire of the
//                  in-flight global_load_lds prefetches
//   [16384,32768)  phase-A x3 panel / WU staging passes (time-shared)
//   [0,16384)      epilogue x'' panel (after chunk loop)
// Staging is global_load_lds (16B): no ds_writes, no VGPR round trip; the
// end-of-chunk __syncthreads drains vmcnt — loads fly across the whole compute.
__global__ __launch_bounds__(256, 4) void k_fused(
    const int* __restrict__ p_val, const int* __restrict__ a_tok, const int* __restrict__ b_tok,
    const float* __restrict__ SC, const __bf16* __restrict__ O0, const __bf16* __restrict__ O1,
    const __bf16* __restrict__ O2, const __bf16* __restrict__ O3g, const __bf16* __restrict__ M3B,
    const __bf16* __restrict__ W1f, const __bf16* __restrict__ W2f, const __bf16* __restrict__ WUf,
    const float* __restrict__ b1, const float* __restrict__ b2, const float* __restrict__ bun,
    float* __restrict__ out)
{
    __shared__ __align__(16) char smem[39936];
    char* sX3 = smem + 16384;              // x3 panel, 64 x 256 B, phase A only
    float* sB1 = (float*)(smem + 37888);

    int tid = threadIdx.x;
    int wv = tid >> 6, l = tid & 63, lr = l & 15, quad = l >> 4;
    int tbase = blockIdx.x * 64 + wv * 16;

    const char* gW1 = (const char*)W1f;
    const char* gW2 = (const char*)W2f;

    // W1 chunk-0 async staging issued FIRST — in flight during phase A
    gl_lds16(gW1 + tid*16,       smem + tid*16);
    gl_lds16(gW1 + (tid+256)*16, smem + (tid+256)*16);
    // b1 -> LDS (region untouched by phase A)
    sB1[tid] = b1[tid]; sB1[tid+256] = b1[tid+256];

    // ---------- phase A: attention; wave-private 16 rows ----------
    {
        int s = tid >> 2, h = tid & 3;
        int gs = blockIdx.x * 64 + s;
        int p = p_val[gs], ta = a_tok[gs], tb = b_tok[gs];

        float wloc[4];
        {
            const float* SCp = SC + p*624;
            float sc0 = SCp[608 + h];
            float sc3 = SCp[612 + h];
            float sc1 = SCp[ta*4 + h] + SCp[616 + h];
            float sc2 = SCp[tb*4 + h] + SCp[620 + h];
            float mx = fmaxf(fmaxf(sc0, sc1), fmaxf(sc2, sc3));
            float e0 = expf(sc0-mx), e1 = expf(sc1-mx), e2 = expf(sc2-mx), e3 = expf(sc3-mx);
            float inv = 1.f / (e0 + e1 + e2 + e3);
            wloc[0] = e0*inv; wloc[1] = e1*inv; wloc[2] = e2*inv; wloc[3] = e3*inv;
        }
        float w[16];
        #pragma unroll
        for (int j = 0; j < 4; j++) w[h*4 + j] = wloc[j];
        #pragma unroll
        for (int m = 1; m < 4; m++) {
            int oh = h ^ m;
            #pragma unroll
            for (int j = 0; j < 4; j++) w[oh*4 + j] = __shfl_xor(wloc[j], m);
        }

        const bf16x8* m3v = (const bf16x8*)(M3B + p*128);
        const bf16x8* t0  = (const bf16x8*)(O0 + p*512);
        const bf16x8* t1  = (const bf16x8*)(O1 + ta*512);
        const bf16x8* t2  = (const bf16x8*)(O2 + tb*512);
        const bf16x8* t3  = (const bf16x8*)O3g;
        #pragma unroll
        for (int jj = 0; jj < 4; jj++) {
            int c8 = h*4 + jj;
            bf16x8 mv = m3v[c8];
            float v[8];
            #pragma unroll
            for (int e = 0; e < 8; e++) v[e] = (float)mv[e];
            #pragma unroll
            for (int hh = 0; hh < 4; hh++) {
                int o8 = hh*16 + c8;
                bf16x8 e0 = t0[o8], e1 = t1[o8], e2 = t2[o8], e3 = t3[o8];
                float w0 = w[hh*4+0], w1 = w[hh*4+1], w2 = w[hh*4+2], w3 = w[hh*4+3];
                #pragma unroll
                for (int e = 0; e < 8; e++)
                    v[e] += w0*(float)e0[e] + w1*(float)e1[e] + w2*(float)e2[e] + w3*(float)e3[e];
            }
            bf16x8 st;
            #pragma unroll
            for (int e = 0; e < 8; e++) st[e] = (__bf16)v[e];
            *(bf16x8*)(sX3 + s*256 + ((c8*16) ^ ((s&7)<<4))) = st;
        }
    }
    asm volatile("s_waitcnt lgkmcnt(0)" ::: "memory");
    __builtin_amdgcn_sched_barrier(0);

    // A-fragments from wave-private rows (same-wave write->read, lgkm-ordered)
    bf16x8 a[4];
    {
        int arow = wv*16 + lr;                         // arow&7 == lr&7
        #pragma unroll
        for (int kb = 0; kb < 4; kb++)
            a[kb] = *(const bf16x8*)(sX3 + arow*256 + ((kb*64 + quad*16) ^ ((lr&7)<<4)));
    }
    __syncthreads();   // drains vmcnt: W1 chunk0 staged; x3 consumed by all
    // W2 chunk-0 into [16384,24576) — x3 now dead
    gl_lds16(gW2 + tid*16,       smem + 16384 + tid*16);
    gl_lds16(gW2 + (tid+256)*16, smem + 16384 + (tid+256)*16);
    __syncthreads();   // chunk 0 fully staged

    char* sPanH = smem + 32768 + wv*1280;  // H panel: 16 x 40 bf16, wave-private

    f32x4 acc2[8];
    #pragma unroll
    for (int i = 0; i < 8; i++) acc2[i] = (f32x4){0.f, 0.f, 0.f, 0.f};

    for (int cc = 0; cc < 16; cc++) {
        int pb = cc & 1;
        char* w1b = smem + pb*8192;
        char* w2b = smem + 16384 + pb*8192;
        if (cc < 15) {  // async-stage next chunk into the other buffers
            const char* g1 = gW1 + (cc+1)*8192;
            const char* g2 = gW2 + (cc+1)*8192;
            char* d1 = smem + (pb^1)*8192;
            char* d2 = smem + 16384 + (pb^1)*8192;
            gl_lds16(g1 + tid*16,       d1 + tid*16);
            gl_lds16(g1 + (tid+256)*16, d1 + (tid+256)*16);
            gl_lds16(g2 + tid*16,       d2 + tid*16);
            gl_lds16(g2 + (tid+256)*16, d2 + (tid+256)*16);
        }
        // MLP1: 2 col-groups of 16 (bias from LDS — lgkm domain)
        #pragma unroll
        for (int nbl = 0; nbl < 2; nbl++) {
            float bv = sB1[cc*32 + nbl*16 + lr];
            f32x4 acc = (f32x4){bv, bv, bv, bv};
            #pragma unroll
            for (int kb = 0; kb < 4; kb++) {
                bf16x8 w1 = *(const bf16x8*)(w1b + ((nbl*4 + kb)*64 + l)*16);
                acc = __builtin_amdgcn_mfma_f32_16x16x32_bf16(a[kb], w1, acc, 0, 0, 0);
            }
            #pragma unroll
            for (int r = 0; r < 4; r++)
                *(__bf16*)(sPanH + (((quad*4 + r)*40) + nbl*16 + lr)*2) = (__bf16)fmaxf(acc[r], 0.f);
        }
        asm volatile("s_waitcnt lgkmcnt(0)" ::: "memory");
        __builtin_amdgcn_sched_barrier(0);
        // MLP2 partial: this chunk's 32-wide K block
        {
            bf16x8 h = *(const bf16x8*)(sPanH + (lr*40 + quad*8)*2);
            #pragma unroll
            for (int nb2 = 0; nb2 < 8; nb2++) {
                bf16x8 w2 = *(const bf16x8*)(w2b + (nb2*64 + l)*16);
                acc2[nb2] = __builtin_amdgcn_mfma_f32_16x16x32_bf16(h, w2, acc2[nb2], 0, 0, 0);
            }
        }
        __syncthreads();   // drains vmcnt -> next chunk staged
    }

    // residual via identity-matrix MFMA
    #pragma unroll
    for (int nb2 = 0; nb2 < 8; nb2++) {
        int kb = nb2 >> 1;
        bf16x8 bi;
        #pragma unroll
        for (int j = 0; j < 8; j++)
            bi[j] = (kb*32 + quad*8 + j == nb2*16 + lr) ? (__bf16)1.0f : (__bf16)0.0f;
        acc2[nb2] = __builtin_amdgcn_mfma_f32_16x16x32_bf16(a[kb], bi, acc2[nb2], 0, 0, 0);
    }

    // x'' = acc2 + b2 -> swizzled epilogue panel at [0,16384), wave-private rows
    #pragma unroll
    for (int nb2 = 0; nb2 < 8; nb2++) {
        int n = nb2*16 + lr;
        float bv = b2[n];
        #pragma unroll
        for (int r = 0; r < 4; r++) {
            float v = acc2[nb2][r] + bv;
            int row = wv*16 + quad*4 + r;
            *(__bf16*)(smem + row*256 + ((n*2) ^ ((row&7)<<4))) = (__bf16)v;
        }
    }
    asm volatile("s_waitcnt lgkmcnt(0)" ::: "memory");
    __builtin_amdgcn_sched_barrier(0);
    bf16x8 au[4];
    {
        int arow = wv*16 + lr;
        #pragma unroll
        for (int kb = 0; kb < 4; kb++)
            au[kb] = *(const bf16x8*)(smem + arow*256 + ((kb*64 + quad*16) ^ ((lr&7)<<4)));
    }

    // unembed: WU async-staged through [16384,32768) in 3 passes
    const char* gWU = (const char*)WUf;
    char* sWU = smem + 16384;
    #pragma unroll
    for (int q = 0; q < 3; q++) {
        __syncthreads();                   // previous pass fully read
        if (q < 2) {
            const char* g = gWU + q*16384;
            gl_lds16(g + tid*16,       sWU + tid*16);
            gl_lds16(g + (tid+256)*16, sWU + (tid+256)*16);
            gl_lds16(g + (tid+512)*16, sWU + (tid+512)*16);
            gl_lds16(g + (tid+768)*16, sWU + (tid+768)*16);
        } else {
            const char* g = gWU + 32768;
            gl_lds16(g + tid*16,       sWU + tid*16);
            gl_lds16(g + (tid+256)*16, sWU + (tid+256)*16);
        }
        __syncthreads();                   // drains vmcnt -> pass staged
        int ntn = (q < 2) ? 4 : 2;
        for (int ntl = 0; ntl < ntn; ntl++) {
            int nt = q*4 + ntl;
            int n = nt*16 + lr;
            float bv = (n < 150) ? bun[n] : 0.f;
            f32x4 acc = (f32x4){bv, bv, bv, bv};
            #pragma unroll
            for (int kb = 0; kb < 4; kb++) {
                bf16x8 wu = *(const bf16x8*)(sWU + ((ntl*4 + kb)*64 + l)*16);
                acc = __builtin_amdgcn_mfma_f32_16x16x32_bf16(au[kb], wu, acc, 0, 0, 0);
            }
            if (n < 150) {
                #pragma unroll
                for (int r = 0; r < 4; r++) {
                    int rowg = tbase + quad*4 + r;
                    out[rowg*150 + n] = acc[r];
                }
            }
        }
    }
}

// ============================ launcher ======================================
extern "C" void kernel_launch(void* const* d_in, const int* in_sizes, int n_in,
                              void* d_out, int out_size, void* d_ws, size_t ws_size,
                              hipStream_t stream) {
    const int*   p_val = (const int*)d_in[0];
    const int*   a_tok = (const int*)d_in[1];
    const int*   b_tok = (const int*)d_in[2];
    const float* tok   = (const float*)d_in[3];
    const float* pos   = (const float*)d_in[4];
    const float* W_mem = (const float*)d_in[5];
    const float* b_mem = (const float*)d_in[6];
    const float* W_sur = (const float*)d_in[7];
    const float* b_sur = (const float*)d_in[8];
    const float* W_m2r = (const float*)d_in[9];
    const float* b_m2r = (const float*)d_in[10];
    const float* W_Q   = (const float*)d_in[11];
    const float* W_K   = (const float*)d_in[12];
    const float* W_V   = (const float*)d_in[13];
    const float* W_O   = (const float*)d_in[14];
    const float* W1    = (const float*)d_in[15];
    const float* b1    = (const float*)d_in[16];
    const float* W2    = (const float*)d_in[17];
    const float* b2    = (const float*)d_in[18];
    const float* WU    = (const float*)d_in[19];
    const float* bun   = (const float*)d_in[20];
    float* out = (float*)d_out;

    float* ws = (float*)d_ws;
    float* memvec = ws + OFF_MEMVEC;
    float* x3base = ws + OFF_X3BASE;
    float* KE     = ws + OFF_KE;
    float* KP     = ws + OFF_KP;
    float* SC     = ws + OFF_SC;
    __bf16* O0    = (__bf16*)(ws + OFF_O0);
    __bf16* O1    = (__bf16*)(ws + OFF_O1);
    __bf16* O2    = (__bf16*)(ws + OFF_O2);
    __bf16* O3    = (__bf16*)(ws + OFF_O3);
    __bf16* M3B   = (__bf16*)(ws + OFF_M3B);
    __bf16* W1f   = (__bf16*)(ws + OFF_W1F);
    __bf16* W2f   = (__bf16*)(ws + OFF_W2F);
    __bf16* WUf   = (__bf16*)(ws + OFF_WUF);

    k_P1a<<<307, 256, 0, stream>>>(tok, pos, W_mem, b_mem, W_sur, b_sur, W_m2r, b_m2r,
                                   W_K, memvec, x3base, KE, KP);
    k_P2x<<<825, 256, 0, stream>>>(memvec, x3base, W_Q, W_V, W_O, KE, KP,
                                   tok, pos, W1, W2, WU,
                                   SC, M3B, O0, O1, O2, O3, W1f, W2f, WUf);
    k_fused<<<NBATCH/64, 256, 0, stream>>>(p_val, a_tok, b_tok, SC, O0, O1, O2, O3, M3B,
                                           W1f, W2f, WUf, b1, b2, bun, out);
}